// Round 17
// baseline (557.991 us; speedup 1.0000x reference)
//
#include <hip/hip_runtime.h>
#include <hip/hip_bf16.h>
#include <stddef.h>

// Sizes: N=4, C=64, F=256, T=256, B=N*F=1024, D=128, H=32, 4H=128, NG=384

typedef __bf16 bf16x8 __attribute__((ext_vector_type(8)));
typedef float f32x4 __attribute__((ext_vector_type(4)));

__device__ __forceinline__ ushort f2bf(float x) {   // RTNE
    uint u = __builtin_bit_cast(uint, x);
    uint r = (u + 0x7fffu + ((u >> 16) & 1u)) >> 16;
    return (ushort)r;
}

__device__ __forceinline__ float fsig(float x) {
    return __builtin_amdgcn_rcpf(1.f + __expf(-x));
}
__device__ __forceinline__ float ftanh(float x) {
    return 1.f - 2.f * __builtin_amdgcn_rcpf(__expf(2.f * x) + 1.f);
}
__device__ __forceinline__ float wredsum(float v) {
#pragma unroll
    for (int off = 32; off; off >>= 1) v += __shfl_xor(v, off);
    return v;
}
__device__ __forceinline__ float hredsum(float v) {
#pragma unroll
    for (int off = 16; off; off >>= 1) v += __shfl_xor(v, off);
    return v;
}

// ---------------------------------------------------------------------------
// Kernel 1: inputs [N,C,F,T,2] -> xn [B,T,128] (bf16) with LN1 fused.
// ---------------------------------------------------------------------------
__global__ __launch_bounds__(256) void k_prep(const float* __restrict__ in,
                                              const float* __restrict__ g1,
                                              const float* __restrict__ b1,
                                              ushort* __restrict__ xn) {
    __shared__ float xl[32][129];
    const int n = blockIdx.z, f = blockIdx.y, t0 = blockIdx.x * 32;
    const int tid = threadIdx.x;
    const int c = tid >> 2, q = tid & 3;
    const float* src = in + ((size_t)(n * 64 + c) * 256 + f) * 512 + t0 * 2 + q * 16;
#pragma unroll
    for (int e = 0; e < 4; ++e) {
        float4 v4 = *(const float4*)(src + e * 4);
        int dt = q * 8 + e * 2;
        xl[dt][c]          = v4.x;
        xl[dt][c + 64]     = v4.y;
        xl[dt + 1][c]      = v4.z;
        xl[dt + 1][c + 64] = v4.w;
    }
    __syncthreads();
    const int lane = tid & 63, w = tid >> 6;
    const int b = n * 256 + f;
#pragma unroll 1
    for (int r = 0; r < 8; ++r) {
        int dt = w * 8 + r;
        float a = xl[dt][lane], bb = xl[dt][lane + 64];
        float s = wredsum(a + bb);
        float mean = s * 0.0078125f;
        float da = a - mean, db = bb - mean;
        float var = wredsum(da * da + db * db) * 0.0078125f;
        float inv = __builtin_amdgcn_rsqf(var + 1e-5f);
        size_t base = ((size_t)b * 256 + (t0 + dt)) * 128;
        xn[base + lane]      = f2bf(da * inv * g1[lane] + b1[lane]);
        xn[base + lane + 64] = f2bf(db * inv * g1[lane + 64] + b1[lane + 64]);
    }
}

// ---------------------------------------------------------------------------
// Kernel 2 (MFMA): gx[M,384](bf16) = xn[M,128](bf16) @ Wcat^T + (bih+bhh)
// One block per 128-row m-tile; loops l=0..2 (A staged once, W restaged).
// Gate storage permuted (round-8 formula): s = (j>>3)*32 + (j&7)*4 + gi
// so k_lstm lane koct reads a contiguous 64B chunk [koct*32, +32) and its
// MFMA D-fragment directly matches the next step's B-fragment (h in regs).
// ---------------------------------------------------------------------------
__global__ __launch_bounds__(256) void k_gemm(const ushort* __restrict__ xn,
                                              const float* __restrict__ Wq,
                                              const float* __restrict__ Wk,
                                              const float* __restrict__ Wv,
                                              const float* __restrict__ bihq, const float* __restrict__ bhhq,
                                              const float* __restrict__ bihk, const float* __restrict__ bhhk,
                                              const float* __restrict__ bihv, const float* __restrict__ bhhv,
                                              ushort* __restrict__ gx) {
    __shared__ ushort a_lds[128 * 136];
    __shared__ ushort w_lds[128 * 136];
    const int tid = threadIdx.x;
    const int m0 = blockIdx.x * 128;

    // stage A once: 128 rows x 128 bf16
#pragma unroll
    for (int p = 0; p < 8; ++p) {
        int idx = p * 256 + tid;
        int r = idx >> 4, c = idx & 15;
        *(uint4*)&a_lds[r * 136 + c * 8] =
            *(const uint4*)(xn + (size_t)(m0 + r) * 128 + c * 8);
    }

    const int w = tid >> 6, lane = tid & 63;
    const int wr = w >> 1, wc = w & 1;
    const int row16 = lane & 15, koct = lane >> 4;

#pragma unroll 1
    for (int l = 0; l < 3; ++l) {
        const float* W   = (l == 0) ? Wq   : (l == 1) ? Wk   : Wv;
        const float* bih = (l == 0) ? bihq : (l == 1) ? bihk : bihv;
        const float* bhh = (l == 0) ? bhhq : (l == 1) ? bhhk : bhhv;
        __syncthreads();   // previous-l readers done (and A writes ordered)
        // stage W_l: 128 gate-rows x 128 fp32 -> bf16
#pragma unroll
        for (int p = 0; p < 8; ++p) {
            int idx = p * 256 + tid;
            int r = idx >> 4, c = idx & 15;
            const float* wp = W + (size_t)r * 128 + c * 8;
            float4 wa = *(const float4*)wp;
            float4 wb = *(const float4*)(wp + 4);
            union { ushort u[8]; uint4 v; } pk;
            pk.u[0] = f2bf(wa.x); pk.u[1] = f2bf(wa.y); pk.u[2] = f2bf(wa.z); pk.u[3] = f2bf(wa.w);
            pk.u[4] = f2bf(wb.x); pk.u[5] = f2bf(wb.y); pk.u[6] = f2bf(wb.z); pk.u[7] = f2bf(wb.w);
            *(uint4*)&w_lds[r * 136 + c * 8] = pk.v;
        }
        __syncthreads();

        f32x4 acc[4][4];
#pragma unroll
        for (int mi = 0; mi < 4; ++mi)
#pragma unroll
            for (int ni = 0; ni < 4; ++ni) acc[mi][ni] = (f32x4){0.f, 0.f, 0.f, 0.f};

#pragma unroll
        for (int ki = 0; ki < 4; ++ki) {
            bf16x8 af[4], bfr[4];
#pragma unroll
            for (int mi = 0; mi < 4; ++mi)
                af[mi] = *(const bf16x8*)&a_lds[(wr * 64 + mi * 16 + row16) * 136 + ki * 32 + koct * 8];
#pragma unroll
            for (int ni = 0; ni < 4; ++ni)
                bfr[ni] = *(const bf16x8*)&w_lds[(wc * 64 + ni * 16 + row16) * 136 + ki * 32 + koct * 8];
#pragma unroll
            for (int mi = 0; mi < 4; ++mi)
#pragma unroll
                for (int ni = 0; ni < 4; ++ni)
                    acc[mi][ni] = __builtin_amdgcn_mfma_f32_16x16x32_bf16(af[mi], bfr[ni], acc[mi][ni], 0, 0, 0);
        }

        // epilogue: bias + s-permuted scalar stores (block owns full lines)
#pragma unroll
        for (int ni = 0; ni < 4; ++ni) {
            int g = wc * 64 + ni * 16 + row16;         // gate 0..127
            float bsv = bih[g] + bhh[g];
            int j = g & 31, gi = g >> 5;
            int s = (j >> 3) * 32 + (j & 7) * 4 + gi;
#pragma unroll
            for (int mi = 0; mi < 4; ++mi)
#pragma unroll
                for (int q = 0; q < 4; ++q) {
                    size_t m = (size_t)m0 + wr * 64 + mi * 16 + koct * 4 + q;
                    gx[m * 384 + l * 128 + s] = f2bf(acc[mi][ni][q] + bsv);
                }
        }
    }
}

// ---------------------------------------------------------------------------
// Kernel 3 (MFMA LSTM, register-only, single wave — round-8/9 structure):
// 1 wave per block; wave owns 16 seqs; NO barriers in the loop (race-free by
// construction). __launch_bounds__(64,1) lifts the VGPR cap so the depth-4
// prefetch stays resident (rounds 8/9 were sunk at VGPR<=76).
// ---------------------------------------------------------------------------
__global__ __launch_bounds__(64, 1) void k_lstm(const ushort* __restrict__ gx,
                                                const float* __restrict__ Whq,
                                                const float* __restrict__ Whk,
                                                const float* __restrict__ Whv,
                                                ushort* __restrict__ qkv) {
    const int lane = threadIdx.x & 63;
    const int r16 = lane & 15, koct = lane >> 4;
    const int l = blockIdx.x >> 6, bgrp = blockIdx.x & 63;
    const int b = bgrp * 16 + r16;
    const float* Wh = (l == 0) ? Whq : (l == 1) ? Whk : Whv;

    // A-fragment for tile g: A-row r16 -> position P = 16g + r16
    bf16x8 wf[8];
#pragma unroll
    for (int g = 0; g < 8; ++g) {
        int P = g * 16 + r16;
        int jA = 8 * ((P >> 2) & 3) + (P >> 4);
        int giA = P & 3;
        const float* wp = Wh + (size_t)(giA * 32 + jA) * 32 + koct * 8;
        float4 wa = *(const float4*)wp;
        float4 wb = *(const float4*)(wp + 4);
        union { ushort u[8]; bf16x8 v; } pk;
        pk.u[0] = f2bf(wa.x); pk.u[1] = f2bf(wa.y); pk.u[2] = f2bf(wa.z); pk.u[3] = f2bf(wa.w);
        pk.u[4] = f2bf(wb.x); pk.u[5] = f2bf(wb.y); pk.u[6] = f2bf(wb.z); pk.u[7] = f2bf(wb.w);
        wf[g] = pk.v;
    }

    // per-lane gx base: contiguous 64B chunk s in [koct*32, +32)
    const ushort* gp = gx + (size_t)b * 98304 + l * 128 + koct * 32;  // 98304=256*384
    uint4 pf[4][4];                    // depth-4 prefetch, 64B per step
#pragma unroll
    for (int tt = 0; tt < 4; ++tt)
#pragma unroll
        for (int i = 0; i < 4; ++i)
            pf[tt][i] = *(const uint4*)(gp + (size_t)tt * 384 + i * 8);

    float cst[8] = {0.f, 0.f, 0.f, 0.f, 0.f, 0.f, 0.f, 0.f};
    uint4 z4 = make_uint4(0, 0, 0, 0);
    bf16x8 hf = __builtin_bit_cast(bf16x8, z4);   // h_{-1} = 0
    ushort* outp = qkv + ((size_t)(l * 1024 + b)) * 8192 + koct * 8;

#pragma unroll 4
    for (int t = 0; t < 256; ++t) {
        const int sl = t & 3;          // static after unroll-4
        uint u[16];
#pragma unroll
        for (int i = 0; i < 4; ++i) {
            u[4 * i]     = pf[sl][i].x;
            u[4 * i + 1] = pf[sl][i].y;
            u[4 * i + 2] = pf[sl][i].z;
            u[4 * i + 3] = pf[sl][i].w;
        }
        int tn = (t + 4 < 256) ? t + 4 : 255;
#pragma unroll
        for (int i = 0; i < 4; ++i)
            pf[sl][i] = *(const uint4*)(gp + (size_t)tn * 384 + i * 8);

        f32x4 acc[8];
#pragma unroll
        for (int g = 0; g < 8; ++g)
#pragma unroll
            for (int q = 0; q < 4; ++q) {
                int v = g * 4 + q;
                uint w32 = u[v >> 1];
                acc[g][q] = __builtin_bit_cast(float, (v & 1) ? (w32 & 0xffff0000u) : (w32 << 16));
            }
#pragma unroll
        for (int g = 0; g < 8; ++g)
            acc[g] = __builtin_amdgcn_mfma_f32_16x16x32_bf16(wf[g], hf, acc[g], 0, 0, 0);

        // nonlinearity: acc[g][0..3] = (i, f, g, o) for j = 8*koct + g
        float hv[8];
#pragma unroll
        for (int g = 0; g < 8; ++g) {
            float gi = acc[g][0], gf = acc[g][1], gg = acc[g][2], go = acc[g][3];
            float cN = fsig(gf) * cst[g] + fsig(gi) * ftanh(gg);
            cst[g] = cN;
            hv[g] = fsig(go) * ftanh(cN);
        }
        uint4 hp;
        __asm__ volatile("v_cvt_pk_bf16_f32 %0, %1, %2" : "=v"(hp.x) : "v"(hv[0]), "v"(hv[1]));
        __asm__ volatile("v_cvt_pk_bf16_f32 %0, %1, %2" : "=v"(hp.y) : "v"(hv[2]), "v"(hv[3]));
        __asm__ volatile("v_cvt_pk_bf16_f32 %0, %1, %2" : "=v"(hp.z) : "v"(hv[4]), "v"(hv[5]));
        __asm__ volatile("v_cvt_pk_bf16_f32 %0, %1, %2" : "=v"(hp.w) : "v"(hv[6]), "v"(hv[7]));
        hf = __builtin_bit_cast(bf16x8, hp);        // next step's B-fragment
        *(uint4*)(outp + (size_t)t * 32) = hp;      // q/k/v output
    }
}

// ---------------------------------------------------------------------------
// Kernel 4 (MFMA): attention. 1 block per b, 4 waves x 64 q-rows each.
// ---------------------------------------------------------------------------
__global__ __launch_bounds__(256) void k_attn(const ushort* __restrict__ qkvb,
                                              float* __restrict__ wvout) {
    __shared__ ushort k_sw[256 * 32];      // 16 KiB
    __shared__ ushort vt_sw[32 * 256];     // 16 KiB
    __shared__ ushort p_sw[4][16 * 256];   // 32 KiB (per-wave private)
    const int tid = threadIdx.x, w = tid >> 6, lane = tid & 63;
    const int b = blockIdx.x;
    const ushort* qb = qkvb + (size_t)b * 8192;
    const ushort* kb = qkvb + 8388608 + (size_t)b * 8192;
    const ushort* vb = qkvb + 16777216 + (size_t)b * 8192;
#pragma unroll
    for (int p = 0; p < 4; ++p) {
        int idx = p * 256 + tid;           // 0..1023 chunks of 8 bf16
        int s = idx >> 2, cc = idx & 3;
        uint4 kv = *(const uint4*)(kb + s * 32 + cc * 8);
        int cK = cc ^ ((s >> 1) & 3);
        *(uint4*)&k_sw[s * 32 + cK * 8] = kv;
        uint4 vv = *(const uint4*)(vb + s * 32 + cc * 8);
        union { uint4 v; ushort u[8]; } un; un.v = vv;
#pragma unroll
        for (int e = 0; e < 8; ++e) {
            int row = cc * 8 + e;
            vt_sw[row * 256 + (((s >> 3) ^ (row & 7)) << 3) + (s & 7)] = un.u[e];
        }
    }
    __syncthreads();
    const int r16 = lane & 15, koct = lane >> 4;
    ushort* pw = p_sw[w];
    bf16x8 qf[4];
#pragma unroll
    for (int i = 0; i < 4; ++i) {
        int t = (w * 4 + i) * 16 + r16;
        qf[i] = *(const bf16x8*)(qb + t * 32 + koct * 8);
    }
#pragma unroll 1
    for (int i = 0; i < 4; ++i) {
        const int tb = (w * 4 + i) * 16;
        f32x4 acc[16];
#pragma unroll
        for (int st = 0; st < 16; ++st) acc[st] = (f32x4){0.f, 0.f, 0.f, 0.f};
#pragma unroll
        for (int st = 0; st < 16; ++st) {
            int s = st * 16 + r16;
            int cK = koct ^ ((s >> 1) & 3);
            bf16x8 kf = *(const bf16x8*)&k_sw[s * 32 + cK * 8];
            acc[st] = __builtin_amdgcn_mfma_f32_16x16x32_bf16(qf[i], kf, acc[st], 0, 0, 0);
        }
        float mx[4] = {-1e30f, -1e30f, -1e30f, -1e30f};
#pragma unroll
        for (int st = 0; st < 16; ++st) {
            int s = st * 16 + r16;
#pragma unroll
            for (int q = 0; q < 4; ++q) {
                int t = tb + koct * 4 + q;
                float v = (s <= t) ? acc[st][q] * 0.25f : 0.f;
                acc[st][q] = v;
                mx[q] = fmaxf(mx[q], v);
            }
        }
#pragma unroll
        for (int off = 1; off < 16; off <<= 1)
#pragma unroll
            for (int q = 0; q < 4; ++q) mx[q] = fmaxf(mx[q], __shfl_xor(mx[q], off));
        float sm[4] = {0.f, 0.f, 0.f, 0.f};
#pragma unroll
        for (int st = 0; st < 16; ++st)
#pragma unroll
            for (int q = 0; q < 4; ++q) {
                float p = __expf(acc[st][q] - mx[q]);
                acc[st][q] = p; sm[q] += p;
            }
#pragma unroll
        for (int off = 1; off < 16; off <<= 1)
#pragma unroll
            for (int q = 0; q < 4; ++q) sm[q] += __shfl_xor(sm[q], off);
        float rs[4];
#pragma unroll
        for (int q = 0; q < 4; ++q) rs[q] = __builtin_amdgcn_rcpf(sm[q]);
#pragma unroll
        for (int st = 0; st < 16; ++st) {
            int schunk = st * 2 + (r16 >> 3), sl = r16 & 7;
#pragma unroll
            for (int q = 0; q < 4; ++q) {
                int tl = koct * 4 + q;
                pw[tl * 256 + ((schunk ^ (tl & 7)) << 3) + sl] = f2bf(acc[st][q] * rs[q]);
            }
        }
        __asm__ volatile("s_waitcnt lgkmcnt(0)" ::: "memory");
        f32x4 oa[2];
        oa[0] = (f32x4){0.f, 0.f, 0.f, 0.f};
        oa[1] = (f32x4){0.f, 0.f, 0.f, 0.f};
#pragma unroll
        for (int ks = 0; ks < 8; ++ks) {
            int kc = ks * 4 + koct;
            bf16x8 pa = *(const bf16x8*)&pw[r16 * 256 + ((kc ^ (r16 & 7)) << 3)];
#pragma unroll
            for (int n = 0; n < 2; ++n) {
                int row = n * 16 + r16;
                bf16x8 vf = *(const bf16x8*)&vt_sw[row * 256 + ((kc ^ (row & 7)) << 3)];
                oa[n] = __builtin_amdgcn_mfma_f32_16x16x32_bf16(pa, vf, oa[n], 0, 0, 0);
            }
        }
#pragma unroll
        for (int n = 0; n < 2; ++n)
#pragma unroll
            for (int q = 0; q < 4; ++q)
                wvout[((size_t)b * 256 + tb + koct * 4 + q) * 32 + n * 16 + r16] = oa[n][q];
    }
}

// ---------------------------------------------------------------------------
// Kernel 5 (round-13): LN2 + complex linear via MFMA (K=32) + one-pass LN3
// + PReLU + residual. (unchanged)
// ---------------------------------------------------------------------------
__global__ __launch_bounds__(256) void k_post(const float* __restrict__ wv,
                                              const float* __restrict__ in,
                                              const float* __restrict__ g2,
                                              const float* __restrict__ b2,
                                              const float* __restrict__ Wr,
                                              const float* __restrict__ br,
                                              const float* __restrict__ Wi,
                                              const float* __restrict__ bi,
                                              const float* __restrict__ g3,
                                              const float* __restrict__ b3,
                                              const float* __restrict__ pa,
                                              float* __restrict__ outp) {
    __shared__ float xv[32][36];          // 144B row stride
    __shared__ float out_s[64][65];
    const int tid = threadIdx.x;
    const int n = blockIdx.z, f = blockIdx.y, t0 = blockIdx.x * 32;
    const int b = n * 256 + f;
    const int lane = tid & 63, w = tid >> 6;
    const int r16 = lane & 15, koct = lane >> 4;
    const int tt = w & 1, ri = w >> 1;

    // stage wv tile [32t][32j]
    for (int idx = tid; idx < 1024; idx += 256) {
        int dt = idx >> 5, j = idx & 31;
        xv[dt][j] = wv[((size_t)b * 256 + t0 + dt) * 32 + j];
    }

    // B-fragments (registers, built once)
    bf16x8 bfr[4];
    float bias_v[4], g3v[4], b3v[4];
    const int kofs = (koct < 2) ? koct * 8 : (koct - 2) * 8;
#pragma unroll
    for (int ct = 0; ct < 4; ++ct) {
        int c = ct * 16 + r16;
        const float* srcW = (ri == 0) ? ((koct < 2) ? Wr : Wi)
                                      : ((koct < 2) ? Wi : Wr);
        float sgn = (ri == 0 && koct >= 2) ? -1.f : 1.f;
        float4 wa = *(const float4*)(srcW + c * 16 + kofs);
        float4 wb = *(const float4*)(srcW + c * 16 + kofs + 4);
        union { ushort u[8]; bf16x8 v; } pk;
        pk.u[0] = f2bf(sgn * wa.x); pk.u[1] = f2bf(sgn * wa.y);
        pk.u[2] = f2bf(sgn * wa.z); pk.u[3] = f2bf(sgn * wa.w);
        pk.u[4] = f2bf(sgn * wb.x); pk.u[5] = f2bf(sgn * wb.y);
        pk.u[6] = f2bf(sgn * wb.z); pk.u[7] = f2bf(sgn * wb.w);
        bfr[ct] = pk.v;
        bias_v[ct] = (ri == 0) ? (br[c] - bi[c]) : (br[c] + bi[c]);
        g3v[ct] = g3[c];
        b3v[ct] = b3[c];
    }
    const float alpha = pa[0];
    __syncthreads();

    // LN2 over 32 per row (two-pass); each 32-lane half one row
#pragma unroll 1
    for (int r = 0; r < 4; ++r) {
        int dt = w * 8 + r * 2 + (lane >> 5);
        int j = lane & 31;
        float v = xv[dt][j];
        float mean = hredsum(v) * 0.03125f;
        float d = v - mean;
        float var = hredsum(d * d) * 0.03125f;
        float inv = __builtin_amdgcn_rsqf(var + 1e-5f);
        xv[dt][j] = d * inv * g2[j] + b2[j];
    }
    __syncthreads();

    // A-fragment: t row = tt*16 + r16, k = koct*8..+7 (fp32 -> bf16)
    const float* xrow = &xv[tt * 16 + r16][koct * 8];
    float4 a0 = *(const float4*)xrow;
    float4 a1 = *(const float4*)(xrow + 4);
    uint4 ap;
    __asm__ volatile("v_cvt_pk_bf16_f32 %0, %1, %2" : "=v"(ap.x) : "v"(a0.x), "v"(a0.y));
    __asm__ volatile("v_cvt_pk_bf16_f32 %0, %1, %2" : "=v"(ap.y) : "v"(a0.z), "v"(a0.w));
    __asm__ volatile("v_cvt_pk_bf16_f32 %0, %1, %2" : "=v"(ap.z) : "v"(a1.x), "v"(a1.y));
    __asm__ volatile("v_cvt_pk_bf16_f32 %0, %1, %2" : "=v"(ap.w) : "v"(a1.z), "v"(a1.w));
    bf16x8 af = __builtin_bit_cast(bf16x8, ap);

    f32x4 acc[4];
#pragma unroll
    for (int ct = 0; ct < 4; ++ct) {
        acc[ct] = (f32x4){0.f, 0.f, 0.f, 0.f};
        acc[ct] = __builtin_amdgcn_mfma_f32_16x16x32_bf16(af, bfr[ct], acc[ct], 0, 0, 0);
    }

    // bias, then one-pass LN3 over c
    float val[4][4];
    float s[4] = {0.f, 0.f, 0.f, 0.f}, sq[4] = {0.f, 0.f, 0.f, 0.f};
#pragma unroll
    for (int ct = 0; ct < 4; ++ct)
#pragma unroll
        for (int q = 0; q < 4; ++q) {
            float v = acc[ct][q] + bias_v[ct];
            val[ct][q] = v;
            s[q] += v;
            sq[q] += v * v;
        }
#pragma unroll
    for (int off = 1; off < 16; off <<= 1)
#pragma unroll
        for (int q = 0; q < 4; ++q) {
            s[q]  += __shfl_xor(s[q], off);
            sq[q] += __shfl_xor(sq[q], off);
        }
#pragma unroll
    for (int q = 0; q < 4; ++q) {
        float m = s[q] * 0.015625f;
        float var = fmaxf(sq[q] * 0.015625f - m * m, 0.f);
        float inv = __builtin_amdgcn_rsqf(var + 1e-5f);
        int t2 = (tt * 16 + koct * 4 + q) * 2 + ri;
#pragma unroll
        for (int ct = 0; ct < 4; ++ct) {
            float nv = (val[ct][q] - m) * inv * g3v[ct] + b3v[ct];
            nv = (nv >= 0.f) ? nv : alpha * nv;
            out_s[ct * 16 + r16][t2] = nv;
        }
    }
    __syncthreads();

    // residual + coalesced store in input layout
    const int cc = tid >> 2, q = tid & 3;
    size_t base = ((size_t)(n * 64 + cc) * 256 + f) * 512 + t0 * 2 + q * 16;
#pragma unroll
    for (int e = 0; e < 4; ++e) {
        float4 iv = *(const float4*)(in + base + e * 4);
        int k0 = q * 16 + e * 4;
        float4 ov;
        ov.x = out_s[cc][k0]     + iv.x;
        ov.y = out_s[cc][k0 + 1] + iv.y;
        ov.z = out_s[cc][k0 + 2] + iv.z;
        ov.w = out_s[cc][k0 + 3] + iv.w;
        *(float4*)(outp + base + e * 4) = ov;
    }
}

// ---------------------------------------------------------------------------
extern "C" void kernel_launch(void* const* d_in, const int* in_sizes, int n_in,
                              void* d_out, int out_size, void* d_ws, size_t ws_size,
                              hipStream_t stream) {
    const float* in   = (const float*)d_in[0];
    const float* g1   = (const float*)d_in[1];
    const float* b1   = (const float*)d_in[2];
    const float* Wq   = (const float*)d_in[3];
    const float* Whq  = (const float*)d_in[4];
    const float* bihq = (const float*)d_in[5];
    const float* bhhq = (const float*)d_in[6];
    const float* Wk   = (const float*)d_in[7];
    const float* Whk  = (const float*)d_in[8];
    const float* bihk = (const float*)d_in[9];
    const float* bhhk = (const float*)d_in[10];
    const float* Wv   = (const float*)d_in[11];
    const float* Whv  = (const float*)d_in[12];
    const float* bihv = (const float*)d_in[13];
    const float* bhhv = (const float*)d_in[14];
    const float* g2   = (const float*)d_in[15];
    const float* b2   = (const float*)d_in[16];
    const float* Wr   = (const float*)d_in[17];
    const float* br   = (const float*)d_in[18];
    const float* Wi   = (const float*)d_in[19];
    const float* bi   = (const float*)d_in[20];
    const float* g3   = (const float*)d_in[21];
    const float* b3   = (const float*)d_in[22];
    const float* pa   = (const float*)d_in[23];
    float* outp = (float*)d_out;

    // workspace layout (bytes):
    // [0, 201326592)            gx  bf16  262144*384*2
    // [201326592, 268435456)    xn  bf16  262144*128*2
    // [268435456, 318767104)    qkv bf16  3*262144*32*2
    // [318767104, 352321536)    wv  fp32  262144*32*4
    ushort* gxb  = (ushort*)d_ws;
    ushort* xnb  = (ushort*)((char*)d_ws + 201326592);
    ushort* qkvb = (ushort*)((char*)d_ws + 268435456);
    float*  wvb  = (float*)((char*)d_ws + 318767104);

    k_prep<<<dim3(8, 256, 4), dim3(256), 0, stream>>>(in, g1, b1, xnb);
    k_gemm<<<dim3(2048), dim3(256), 0, stream>>>(xnb, Wq, Wk, Wv,
                                                 bihq, bhhq, bihk, bhhk, bihv, bhhv, gxb);
    k_lstm<<<dim3(192), dim3(64), 0, stream>>>(gxb, Whq, Whk, Whv, qkvb);
    k_attn<<<dim3(1024), dim3(256), 0, stream>>>(qkvb, wvb);
    k_post<<<dim3(8, 256, 4), dim3(256), 0, stream>>>(wvb, in, g2, b2,
                                                      Wr, br, Wi, bi, g3, b3, pa, outp);
}

// Round 18
// 519.456 us; speedup vs baseline: 1.0742x; 1.0742x over previous
//
#include <hip/hip_runtime.h>
#include <hip/hip_bf16.h>
#include <stddef.h>

// Sizes: N=4, C=64, F=256, T=256, B=N*F=1024, D=128, H=32, 4H=128, NG=384

typedef __bf16 bf16x8 __attribute__((ext_vector_type(8)));
typedef float f32x4 __attribute__((ext_vector_type(4)));

__device__ __forceinline__ ushort f2bf(float x) {   // RTNE
    uint u = __builtin_bit_cast(uint, x);
    uint r = (u + 0x7fffu + ((u >> 16) & 1u)) >> 16;
    return (ushort)r;
}

__device__ __forceinline__ float fsig(float x) {
    return __builtin_amdgcn_rcpf(1.f + __expf(-x));
}
__device__ __forceinline__ float ftanh(float x) {
    return 1.f - 2.f * __builtin_amdgcn_rcpf(__expf(2.f * x) + 1.f);
}
__device__ __forceinline__ float wredsum(float v) {
#pragma unroll
    for (int off = 32; off; off >>= 1) v += __shfl_xor(v, off);
    return v;
}
__device__ __forceinline__ float hredsum(float v) {
#pragma unroll
    for (int off = 16; off; off >>= 1) v += __shfl_xor(v, off);
    return v;
}

// ---------------------------------------------------------------------------
// Kernel 1: inputs [N,C,F,T,2] -> xn [B,T,128] (bf16) with LN1 fused.
// ---------------------------------------------------------------------------
__global__ __launch_bounds__(256) void k_prep(const float* __restrict__ in,
                                              const float* __restrict__ g1,
                                              const float* __restrict__ b1,
                                              ushort* __restrict__ xn) {
    __shared__ float xl[32][129];
    const int n = blockIdx.z, f = blockIdx.y, t0 = blockIdx.x * 32;
    const int tid = threadIdx.x;
    const int c = tid >> 2, q = tid & 3;
    const float* src = in + ((size_t)(n * 64 + c) * 256 + f) * 512 + t0 * 2 + q * 16;
#pragma unroll
    for (int e = 0; e < 4; ++e) {
        float4 v4 = *(const float4*)(src + e * 4);
        int dt = q * 8 + e * 2;
        xl[dt][c]          = v4.x;
        xl[dt][c + 64]     = v4.y;
        xl[dt + 1][c]      = v4.z;
        xl[dt + 1][c + 64] = v4.w;
    }
    __syncthreads();
    const int lane = tid & 63, w = tid >> 6;
    const int b = n * 256 + f;
#pragma unroll 1
    for (int r = 0; r < 8; ++r) {
        int dt = w * 8 + r;
        float a = xl[dt][lane], bb = xl[dt][lane + 64];
        float s = wredsum(a + bb);
        float mean = s * 0.0078125f;
        float da = a - mean, db = bb - mean;
        float var = wredsum(da * da + db * db) * 0.0078125f;
        float inv = __builtin_amdgcn_rsqf(var + 1e-5f);
        size_t base = ((size_t)b * 256 + (t0 + dt)) * 128;
        xn[base + lane]      = f2bf(da * inv * g1[lane] + b1[lane]);
        xn[base + lane + 64] = f2bf(db * inv * g1[lane + 64] + b1[lane + 64]);
    }
}

// ---------------------------------------------------------------------------
// Kernel 2 (MFMA): gx[M,384](bf16) = xn[M,128](bf16) @ Wcat^T + (bih+bhh)
// One block per 128-row m-tile; loops l=0..2 (A staged once, W restaged).
// Gate storage permuted: s = 4*j + gi (j=g&31, gi=g>>5).   [round-13]
// ---------------------------------------------------------------------------
__global__ __launch_bounds__(256) void k_gemm(const ushort* __restrict__ xn,
                                              const float* __restrict__ Wq,
                                              const float* __restrict__ Wk,
                                              const float* __restrict__ Wv,
                                              const float* __restrict__ bihq, const float* __restrict__ bhhq,
                                              const float* __restrict__ bihk, const float* __restrict__ bhhk,
                                              const float* __restrict__ bihv, const float* __restrict__ bhhv,
                                              ushort* __restrict__ gx) {
    __shared__ ushort a_lds[128 * 136];
    __shared__ ushort w_lds[128 * 136];
    const int tid = threadIdx.x;
    const int m0 = blockIdx.x * 128;

#pragma unroll
    for (int p = 0; p < 8; ++p) {
        int idx = p * 256 + tid;
        int r = idx >> 4, c = idx & 15;
        *(uint4*)&a_lds[r * 136 + c * 8] =
            *(const uint4*)(xn + (size_t)(m0 + r) * 128 + c * 8);
    }

    const int w = tid >> 6, lane = tid & 63;
    const int wr = w >> 1, wc = w & 1;
    const int row16 = lane & 15, koct = lane >> 4;

#pragma unroll 1
    for (int l = 0; l < 3; ++l) {
        const float* W   = (l == 0) ? Wq   : (l == 1) ? Wk   : Wv;
        const float* bih = (l == 0) ? bihq : (l == 1) ? bihk : bihv;
        const float* bhh = (l == 0) ? bhhq : (l == 1) ? bhhk : bhhv;
        __syncthreads();
#pragma unroll
        for (int p = 0; p < 8; ++p) {
            int idx = p * 256 + tid;
            int r = idx >> 4, c = idx & 15;
            const float* wp = W + (size_t)r * 128 + c * 8;
            float4 wa = *(const float4*)wp;
            float4 wb = *(const float4*)(wp + 4);
            union { ushort u[8]; uint4 v; } pk;
            pk.u[0] = f2bf(wa.x); pk.u[1] = f2bf(wa.y); pk.u[2] = f2bf(wa.z); pk.u[3] = f2bf(wa.w);
            pk.u[4] = f2bf(wb.x); pk.u[5] = f2bf(wb.y); pk.u[6] = f2bf(wb.z); pk.u[7] = f2bf(wb.w);
            *(uint4*)&w_lds[r * 136 + c * 8] = pk.v;
        }
        __syncthreads();

        f32x4 acc[4][4];
#pragma unroll
        for (int mi = 0; mi < 4; ++mi)
#pragma unroll
            for (int ni = 0; ni < 4; ++ni) acc[mi][ni] = (f32x4){0.f, 0.f, 0.f, 0.f};

#pragma unroll
        for (int ki = 0; ki < 4; ++ki) {
            bf16x8 af[4], bfr[4];
#pragma unroll
            for (int mi = 0; mi < 4; ++mi)
                af[mi] = *(const bf16x8*)&a_lds[(wr * 64 + mi * 16 + row16) * 136 + ki * 32 + koct * 8];
#pragma unroll
            for (int ni = 0; ni < 4; ++ni)
                bfr[ni] = *(const bf16x8*)&w_lds[(wc * 64 + ni * 16 + row16) * 136 + ki * 32 + koct * 8];
#pragma unroll
            for (int mi = 0; mi < 4; ++mi)
#pragma unroll
                for (int ni = 0; ni < 4; ++ni)
                    acc[mi][ni] = __builtin_amdgcn_mfma_f32_16x16x32_bf16(af[mi], bfr[ni], acc[mi][ni], 0, 0, 0);
        }

#pragma unroll
        for (int ni = 0; ni < 4; ++ni) {
            int g = wc * 64 + ni * 16 + row16;         // gate 0..127
            float bsv = bih[g] + bhh[g];
            int j = g & 31, gi = g >> 5;
            int s = j * 4 + gi;
#pragma unroll
            for (int mi = 0; mi < 4; ++mi)
#pragma unroll
                for (int q = 0; q < 4; ++q) {
                    size_t m = (size_t)m0 + wr * 64 + mi * 16 + koct * 4 + q;
                    gx[m * 384 + l * 128 + s] = f2bf(acc[mi][ni][q] + bsv);
                }
        }
    }
}

// ---------------------------------------------------------------------------
// Kernel 3 (MFMA LSTM, 2-wave gate-split + chunked global_load_lds staging):
// Round-13 structure (plain __syncthreads, deterministic) but gx is staged
// into double-buffered LDS in chunks of 4 steps via global_load_lds — the
// per-step barrier's vmcnt drain then costs ~1 residual stall per 4 steps
// instead of a full HBM latency every step. Output store deferred 1 step.
// ---------------------------------------------------------------------------
__global__ __launch_bounds__(128, 1) void k_lstm(const ushort* __restrict__ gx,
                                                 const float* __restrict__ Whq,
                                                 const float* __restrict__ Whk,
                                                 const float* __restrict__ Whv,
                                                 ushort* __restrict__ qkv) {
    __shared__ ushort H[2][16][40];                 // [parity][b][j]
    __shared__ ushort gstage[2][2][4][2][512];      // [buf][wave][t4][piece][lane*8] = 32 KiB
    const int tid = threadIdx.x;
    const int w = tid >> 6, lane = tid & 63;
    const int r16 = lane & 15, koct = lane >> 4;
    const int l = blockIdx.x >> 6, bgrp = blockIdx.x & 63;
    const int b = bgrp * 16 + r16;
    const float* Wh = (l == 0) ? Whq : (l == 1) ? Whk : Whv;

    bf16x8 wf[4];
#pragma unroll
    for (int gg = 0; gg < 4; ++gg) {
        int g = 4 * w + gg;
        int jA = 8 * (r16 >> 2) + g;
        int giA = r16 & 3;
        const float* wp = Wh + (size_t)(giA * 32 + jA) * 32 + koct * 8;
        float4 wa = *(const float4*)wp;
        float4 wb = *(const float4*)(wp + 4);
        union { ushort u[8]; bf16x8 v; } pk;
        pk.u[0] = f2bf(wa.x); pk.u[1] = f2bf(wa.y); pk.u[2] = f2bf(wa.z); pk.u[3] = f2bf(wa.w);
        pk.u[4] = f2bf(wb.x); pk.u[5] = f2bf(wb.y); pk.u[6] = f2bf(wb.z); pk.u[7] = f2bf(wb.w);
        wf[gg] = pk.v;
    }

    // per-lane gx byte base: 32B chunk at s in [32*koct + 16*w, +16)
    const char* gsrc = (const char*)(gx + (size_t)b * 98304 + l * 128 + koct * 32 + w * 16);

    // stage chunk 0 into buf 0 (this wave's slice)
#pragma unroll
    for (int t4 = 0; t4 < 4; ++t4)
#pragma unroll
        for (int i = 0; i < 2; ++i)
            __builtin_amdgcn_global_load_lds(
                (const __attribute__((address_space(1))) uint*)(gsrc + t4 * 768 + i * 16),
                (__attribute__((address_space(3))) uint*)((char*)&gstage[0][w][t4][i][0]),
                16, 0, 0);

    for (int i = tid; i < 320; i += 128) ((uint*)&H[0][0][0])[i] = 0;
    __syncthreads();   // drains chunk-0 loads + orders H init

    float cst[4] = {0.f, 0.f, 0.f, 0.f};
    ushort* outp = qkv + ((size_t)(l * 1024 + b)) * 8192 + koct * 8 + w * 4;
    uint2 hprev = make_uint2(0, 0);

#pragma unroll 1
    for (int c = 0; c < 64; ++c) {
        const int cur = c & 1;
        if (c < 63) {   // stage chunk c+1 into the other buffer
            const char* gs = gsrc + (size_t)(c + 1) * 3072;
#pragma unroll
            for (int t4 = 0; t4 < 4; ++t4)
#pragma unroll
                for (int i = 0; i < 2; ++i)
                    __builtin_amdgcn_global_load_lds(
                        (const __attribute__((address_space(1))) uint*)(gs + t4 * 768 + i * 16),
                        (__attribute__((address_space(3))) uint*)((char*)&gstage[cur ^ 1][w][t4][i][0]),
                        16, 0, 0);
        }
#pragma unroll
        for (int t4 = 0; t4 < 4; ++t4) {
            const int t = c * 4 + t4;
            const int p = t & 1;
            // deferred store of h_{t-1} (ack covered by this step's work)
            if (t > 0) *(uint2*)(outp + (size_t)(t - 1) * 32) = hprev;
            // B-fragment: full h for this lane's k-slice
            bf16x8 hf = *(const bf16x8*)&H[p][r16][koct * 8];
            // gates from LDS (conflict-free lane*16 linear layout)
            uint4 ga = *(const uint4*)&gstage[cur][w][t4][0][lane * 8];
            uint4 gb = *(const uint4*)&gstage[cur][w][t4][1][lane * 8];
            uint u[8] = {ga.x, ga.y, ga.z, ga.w, gb.x, gb.y, gb.z, gb.w};

            f32x4 acc[4];
#pragma unroll
            for (int gg = 0; gg < 4; ++gg)
#pragma unroll
                for (int q = 0; q < 4; ++q) {
                    int v = gg * 4 + q;
                    uint w32 = u[v >> 1];
                    acc[gg][q] = __builtin_bit_cast(float, (v & 1) ? (w32 & 0xffff0000u) : (w32 << 16));
                }
#pragma unroll
            for (int gg = 0; gg < 4; ++gg)
                acc[gg] = __builtin_amdgcn_mfma_f32_16x16x32_bf16(wf[gg], hf, acc[gg], 0, 0, 0);

            float hv[4];
#pragma unroll
            for (int gg = 0; gg < 4; ++gg) {
                float gi = acc[gg][0], gf = acc[gg][1], gg2 = acc[gg][2], go = acc[gg][3];
                float cN = fsig(gf) * cst[gg] + fsig(gi) * ftanh(gg2);
                cst[gg] = cN;
                hv[gg] = fsig(go) * ftanh(cN);
            }
            uint2 hp;
            __asm__ volatile("v_cvt_pk_bf16_f32 %0, %1, %2" : "=v"(hp.x) : "v"(hv[0]), "v"(hv[1]));
            __asm__ volatile("v_cvt_pk_bf16_f32 %0, %1, %2" : "=v"(hp.y) : "v"(hv[2]), "v"(hv[3]));
            *(uint2*)&H[p ^ 1][r16][koct * 8 + w * 4] = hp;
            hprev = hp;
            __syncthreads();
        }
    }
    *(uint2*)(outp + (size_t)255 * 32) = hprev;     // h_255
}

// ---------------------------------------------------------------------------
// Kernel 4 (MFMA): attention. 1 block per b, 4 waves x 64 q-rows each.
// ---------------------------------------------------------------------------
__global__ __launch_bounds__(256) void k_attn(const ushort* __restrict__ qkvb,
                                              float* __restrict__ wvout) {
    __shared__ ushort k_sw[256 * 32];      // 16 KiB
    __shared__ ushort vt_sw[32 * 256];     // 16 KiB
    __shared__ ushort p_sw[4][16 * 256];   // 32 KiB (per-wave private)
    const int tid = threadIdx.x, w = tid >> 6, lane = tid & 63;
    const int b = blockIdx.x;
    const ushort* qb = qkvb + (size_t)b * 8192;
    const ushort* kb = qkvb + 8388608 + (size_t)b * 8192;
    const ushort* vb = qkvb + 16777216 + (size_t)b * 8192;
#pragma unroll
    for (int p = 0; p < 4; ++p) {
        int idx = p * 256 + tid;           // 0..1023 chunks of 8 bf16
        int s = idx >> 2, cc = idx & 3;
        uint4 kv = *(const uint4*)(kb + s * 32 + cc * 8);
        int cK = cc ^ ((s >> 1) & 3);
        *(uint4*)&k_sw[s * 32 + cK * 8] = kv;
        uint4 vv = *(const uint4*)(vb + s * 32 + cc * 8);
        union { uint4 v; ushort u[8]; } un; un.v = vv;
#pragma unroll
        for (int e = 0; e < 8; ++e) {
            int row = cc * 8 + e;
            vt_sw[row * 256 + (((s >> 3) ^ (row & 7)) << 3) + (s & 7)] = un.u[e];
        }
    }
    __syncthreads();
    const int r16 = lane & 15, koct = lane >> 4;
    ushort* pw = p_sw[w];
    bf16x8 qf[4];
#pragma unroll
    for (int i = 0; i < 4; ++i) {
        int t = (w * 4 + i) * 16 + r16;
        qf[i] = *(const bf16x8*)(qb + t * 32 + koct * 8);
    }
#pragma unroll 1
    for (int i = 0; i < 4; ++i) {
        const int tb = (w * 4 + i) * 16;
        f32x4 acc[16];
#pragma unroll
        for (int st = 0; st < 16; ++st) acc[st] = (f32x4){0.f, 0.f, 0.f, 0.f};
#pragma unroll
        for (int st = 0; st < 16; ++st) {
            int s = st * 16 + r16;
            int cK = koct ^ ((s >> 1) & 3);
            bf16x8 kf = *(const bf16x8*)&k_sw[s * 32 + cK * 8];
            acc[st] = __builtin_amdgcn_mfma_f32_16x16x32_bf16(qf[i], kf, acc[st], 0, 0, 0);
        }
        float mx[4] = {-1e30f, -1e30f, -1e30f, -1e30f};
#pragma unroll
        for (int st = 0; st < 16; ++st) {
            int s = st * 16 + r16;
#pragma unroll
            for (int q = 0; q < 4; ++q) {
                int t = tb + koct * 4 + q;
                float v = (s <= t) ? acc[st][q] * 0.25f : 0.f;
                acc[st][q] = v;
                mx[q] = fmaxf(mx[q], v);
            }
        }
#pragma unroll
        for (int off = 1; off < 16; off <<= 1)
#pragma unroll
            for (int q = 0; q < 4; ++q) mx[q] = fmaxf(mx[q], __shfl_xor(mx[q], off));
        float sm[4] = {0.f, 0.f, 0.f, 0.f};
#pragma unroll
        for (int st = 0; st < 16; ++st)
#pragma unroll
            for (int q = 0; q < 4; ++q) {
                float p = __expf(acc[st][q] - mx[q]);
                acc[st][q] = p; sm[q] += p;
            }
#pragma unroll
        for (int off = 1; off < 16; off <<= 1)
#pragma unroll
            for (int q = 0; q < 4; ++q) sm[q] += __shfl_xor(sm[q], off);
        float rs[4];
#pragma unroll
        for (int q = 0; q < 4; ++q) rs[q] = __builtin_amdgcn_rcpf(sm[q]);
#pragma unroll
        for (int st = 0; st < 16; ++st) {
            int schunk = st * 2 + (r16 >> 3), sl = r16 & 7;
#pragma unroll
            for (int q = 0; q < 4; ++q) {
                int tl = koct * 4 + q;
                pw[tl * 256 + ((schunk ^ (tl & 7)) << 3) + sl] = f2bf(acc[st][q] * rs[q]);
            }
        }
        __asm__ volatile("s_waitcnt lgkmcnt(0)" ::: "memory");
        f32x4 oa[2];
        oa[0] = (f32x4){0.f, 0.f, 0.f, 0.f};
        oa[1] = (f32x4){0.f, 0.f, 0.f, 0.f};
#pragma unroll
        for (int ks = 0; ks < 8; ++ks) {
            int kc = ks * 4 + koct;
            bf16x8 pa = *(const bf16x8*)&pw[r16 * 256 + ((kc ^ (r16 & 7)) << 3)];
#pragma unroll
            for (int n = 0; n < 2; ++n) {
                int row = n * 16 + r16;
                bf16x8 vf = *(const bf16x8*)&vt_sw[row * 256 + ((kc ^ (row & 7)) << 3)];
                oa[n] = __builtin_amdgcn_mfma_f32_16x16x32_bf16(pa, vf, oa[n], 0, 0, 0);
            }
        }
#pragma unroll
        for (int n = 0; n < 2; ++n)
#pragma unroll
            for (int q = 0; q < 4; ++q)
                wvout[((size_t)b * 256 + tb + koct * 4 + q) * 32 + n * 16 + r16] = oa[n][q];
    }
}

// ---------------------------------------------------------------------------
// Kernel 5 (round-13): LN2 + complex linear via MFMA (K=32) + one-pass LN3
// + PReLU + residual.
// ---------------------------------------------------------------------------
__global__ __launch_bounds__(256) void k_post(const float* __restrict__ wv,
                                              const float* __restrict__ in,
                                              const float* __restrict__ g2,
                                              const float* __restrict__ b2,
                                              const float* __restrict__ Wr,
                                              const float* __restrict__ br,
                                              const float* __restrict__ Wi,
                                              const float* __restrict__ bi,
                                              const float* __restrict__ g3,
                                              const float* __restrict__ b3,
                                              const float* __restrict__ pa,
                                              float* __restrict__ outp) {
    __shared__ float xv[32][36];          // 144B row stride
    __shared__ float out_s[64][65];
    const int tid = threadIdx.x;
    const int n = blockIdx.z, f = blockIdx.y, t0 = blockIdx.x * 32;
    const int b = n * 256 + f;
    const int lane = tid & 63, w = tid >> 6;
    const int r16 = lane & 15, koct = lane >> 4;
    const int tt = w & 1, ri = w >> 1;

    for (int idx = tid; idx < 1024; idx += 256) {
        int dt = idx >> 5, j = idx & 31;
        xv[dt][j] = wv[((size_t)b * 256 + t0 + dt) * 32 + j];
    }

    bf16x8 bfr[4];
    float bias_v[4], g3v[4], b3v[4];
    const int kofs = (koct < 2) ? koct * 8 : (koct - 2) * 8;
#pragma unroll
    for (int ct = 0; ct < 4; ++ct) {
        int c = ct * 16 + r16;
        const float* srcW = (ri == 0) ? ((koct < 2) ? Wr : Wi)
                                      : ((koct < 2) ? Wi : Wr);
        float sgn = (ri == 0 && koct >= 2) ? -1.f : 1.f;
        float4 wa = *(const float4*)(srcW + c * 16 + kofs);
        float4 wb = *(const float4*)(srcW + c * 16 + kofs + 4);
        union { ushort u[8]; bf16x8 v; } pk;
        pk.u[0] = f2bf(sgn * wa.x); pk.u[1] = f2bf(sgn * wa.y);
        pk.u[2] = f2bf(sgn * wa.z); pk.u[3] = f2bf(sgn * wa.w);
        pk.u[4] = f2bf(sgn * wb.x); pk.u[5] = f2bf(sgn * wb.y);
        pk.u[6] = f2bf(sgn * wb.z); pk.u[7] = f2bf(sgn * wb.w);
        bfr[ct] = pk.v;
        bias_v[ct] = (ri == 0) ? (br[c] - bi[c]) : (br[c] + bi[c]);
        g3v[ct] = g3[c];
        b3v[ct] = b3[c];
    }
    const float alpha = pa[0];
    __syncthreads();

#pragma unroll 1
    for (int r = 0; r < 4; ++r) {
        int dt = w * 8 + r * 2 + (lane >> 5);
        int j = lane & 31;
        float v = xv[dt][j];
        float mean = hredsum(v) * 0.03125f;
        float d = v - mean;
        float var = hredsum(d * d) * 0.03125f;
        float inv = __builtin_amdgcn_rsqf(var + 1e-5f);
        xv[dt][j] = d * inv * g2[j] + b2[j];
    }
    __syncthreads();

    const float* xrow = &xv[tt * 16 + r16][koct * 8];
    float4 a0 = *(const float4*)xrow;
    float4 a1 = *(const float4*)(xrow + 4);
    uint4 ap;
    __asm__ volatile("v_cvt_pk_bf16_f32 %0, %1, %2" : "=v"(ap.x) : "v"(a0.x), "v"(a0.y));
    __asm__ volatile("v_cvt_pk_bf16_f32 %0, %1, %2" : "=v"(ap.y) : "v"(a0.z), "v"(a0.w));
    __asm__ volatile("v_cvt_pk_bf16_f32 %0, %1, %2" : "=v"(ap.z) : "v"(a1.x), "v"(a1.y));
    __asm__ volatile("v_cvt_pk_bf16_f32 %0, %1, %2" : "=v"(ap.w) : "v"(a1.z), "v"(a1.w));
    bf16x8 af = __builtin_bit_cast(bf16x8, ap);

    f32x4 acc[4];
#pragma unroll
    for (int ct = 0; ct < 4; ++ct) {
        acc[ct] = (f32x4){0.f, 0.f, 0.f, 0.f};
        acc[ct] = __builtin_amdgcn_mfma_f32_16x16x32_bf16(af, bfr[ct], acc[ct], 0, 0, 0);
    }

    float val[4][4];
    float s[4] = {0.f, 0.f, 0.f, 0.f}, sq[4] = {0.f, 0.f, 0.f, 0.f};
#pragma unroll
    for (int ct = 0; ct < 4; ++ct)
#pragma unroll
        for (int q = 0; q < 4; ++q) {
            float v = acc[ct][q] + bias_v[ct];
            val[ct][q] = v;
            s[q] += v;
            sq[q] += v * v;
        }
#pragma unroll
    for (int off = 1; off < 16; off <<= 1)
#pragma unroll
        for (int q = 0; q < 4; ++q) {
            s[q]  += __shfl_xor(s[q], off);
            sq[q] += __shfl_xor(sq[q], off);
        }
#pragma unroll
    for (int q = 0; q < 4; ++q) {
        float m = s[q] * 0.015625f;
        float var = fmaxf(sq[q] * 0.015625f - m * m, 0.f);
        float inv = __builtin_amdgcn_rsqf(var + 1e-5f);
        int t2 = (tt * 16 + koct * 4 + q) * 2 + ri;
#pragma unroll
        for (int ct = 0; ct < 4; ++ct) {
            float nv = (val[ct][q] - m) * inv * g3v[ct] + b3v[ct];
            nv = (nv >= 0.f) ? nv : alpha * nv;
            out_s[ct * 16 + r16][t2] = nv;
        }
    }
    __syncthreads();

    const int cc = tid >> 2, q = tid & 3;
    size_t base = ((size_t)(n * 64 + cc) * 256 + f) * 512 + t0 * 2 + q * 16;
#pragma unroll
    for (int e = 0; e < 4; ++e) {
        float4 iv = *(const float4*)(in + base + e * 4);
        int k0 = q * 16 + e * 4;
        float4 ov;
        ov.x = out_s[cc][k0]     + iv.x;
        ov.y = out_s[cc][k0 + 1] + iv.y;
        ov.z = out_s[cc][k0 + 2] + iv.z;
        ov.w = out_s[cc][k0 + 3] + iv.w;
        *(float4*)(outp + base + e * 4) = ov;
    }
}

// ---------------------------------------------------------------------------
extern "C" void kernel_launch(void* const* d_in, const int* in_sizes, int n_in,
                              void* d_out, int out_size, void* d_ws, size_t ws_size,
                              hipStream_t stream) {
    const float* in   = (const float*)d_in[0];
    const float* g1   = (const float*)d_in[1];
    const float* b1   = (const float*)d_in[2];
    const float* Wq   = (const float*)d_in[3];
    const float* Whq  = (const float*)d_in[4];
    const float* bihq = (const float*)d_in[5];
    const float* bhhq = (const float*)d_in[6];
    const float* Wk   = (const float*)d_in[7];
    const float* Whk  = (const float*)d_in[8];
    const float* bihk = (const float*)d_in[9];
    const float* bhhk = (const float*)d_in[10];
    const float* Wv   = (const float*)d_in[11];
    const float* Whv  = (const float*)d_in[12];
    const float* bihv = (const float*)d_in[13];
    const float* bhhv = (const float*)d_in[14];
    const float* g2   = (const float*)d_in[15];
    const float* b2   = (const float*)d_in[16];
    const float* Wr   = (const float*)d_in[17];
    const float* br   = (const float*)d_in[18];
    const float* Wi   = (const float*)d_in[19];
    const float* bi   = (const float*)d_in[20];
    const float* g3   = (const float*)d_in[21];
    const float* b3   = (const float*)d_in[22];
    const float* pa   = (const float*)d_in[23];
    float* outp = (float*)d_out;

    // workspace layout (bytes):
    // [0, 201326592)            gx  bf16  262144*384*2
    // [201326592, 268435456)    xn  bf16  262144*128*2
    // [268435456, 318767104)    qkv bf16  3*262144*32*2
    // [318767104, 352321536)    wv  fp32  262144*32*4
    ushort* gxb  = (ushort*)d_ws;
    ushort* xnb  = (ushort*)((char*)d_ws + 201326592);
    ushort* qkvb = (ushort*)((char*)d_ws + 268435456);
    float*  wvb  = (float*)((char*)d_ws + 318767104);

    k_prep<<<dim3(8, 256, 4), dim3(256), 0, stream>>>(in, g1, b1, xnb);
    k_gemm<<<dim3(2048), dim3(256), 0, stream>>>(xnb, Wq, Wk, Wv,
                                                 bihq, bhhq, bihk, bhhk, bihv, bhhv, gxb);
    k_lstm<<<dim3(192), dim3(128), 0, stream>>>(gxb, Whq, Whk, Whv, qkvb);
    k_attn<<<dim3(1024), dim3(256), 0, stream>>>(qkvb, wvb);
    k_post<<<dim3(8, 256, 4), dim3(256), 0, stream>>>(wvb, in, g2, b2,
                                                      Wr, br, Wi, bi, g3, b3, pa, outp);
}

// Round 19
// 472.001 us; speedup vs baseline: 1.1822x; 1.1005x over previous
//
#include <hip/hip_runtime.h>
#include <hip/hip_bf16.h>
#include <stddef.h>

// Sizes: N=4, C=64, F=256, T=256, B=N*F=1024, D=128, H=32, 4H=128, NG=384

typedef __bf16 bf16x8 __attribute__((ext_vector_type(8)));
typedef float f32x4 __attribute__((ext_vector_type(4)));

__device__ __forceinline__ ushort f2bf(float x) {   // RTNE
    uint u = __builtin_bit_cast(uint, x);
    uint r = (u + 0x7fffu + ((u >> 16) & 1u)) >> 16;
    return (ushort)r;
}

__device__ __forceinline__ float fsig(float x) {
    return __builtin_amdgcn_rcpf(1.f + __expf(-x));
}
__device__ __forceinline__ float ftanh(float x) {
    return 1.f - 2.f * __builtin_amdgcn_rcpf(__expf(2.f * x) + 1.f);
}
__device__ __forceinline__ float wredsum(float v) {
#pragma unroll
    for (int off = 32; off; off >>= 1) v += __shfl_xor(v, off);
    return v;
}
__device__ __forceinline__ float hredsum(float v) {
#pragma unroll
    for (int off = 16; off; off >>= 1) v += __shfl_xor(v, off);
    return v;
}

// ---------------------------------------------------------------------------
// Kernel 1: inputs [N,C,F,T,2] -> xn [B,T,128] (bf16) with LN1 fused.
// ---------------------------------------------------------------------------
__global__ __launch_bounds__(256) void k_prep(const float* __restrict__ in,
                                              const float* __restrict__ g1,
                                              const float* __restrict__ b1,
                                              ushort* __restrict__ xn) {
    __shared__ float xl[32][129];
    const int n = blockIdx.z, f = blockIdx.y, t0 = blockIdx.x * 32;
    const int tid = threadIdx.x;
    const int c = tid >> 2, q = tid & 3;
    const float* src = in + ((size_t)(n * 64 + c) * 256 + f) * 512 + t0 * 2 + q * 16;
#pragma unroll
    for (int e = 0; e < 4; ++e) {
        float4 v4 = *(const float4*)(src + e * 4);
        int dt = q * 8 + e * 2;
        xl[dt][c]          = v4.x;
        xl[dt][c + 64]     = v4.y;
        xl[dt + 1][c]      = v4.z;
        xl[dt + 1][c + 64] = v4.w;
    }
    __syncthreads();
    const int lane = tid & 63, w = tid >> 6;
    const int b = n * 256 + f;
#pragma unroll 1
    for (int r = 0; r < 8; ++r) {
        int dt = w * 8 + r;
        float a = xl[dt][lane], bb = xl[dt][lane + 64];
        float s = wredsum(a + bb);
        float mean = s * 0.0078125f;
        float da = a - mean, db = bb - mean;
        float var = wredsum(da * da + db * db) * 0.0078125f;
        float inv = __builtin_amdgcn_rsqf(var + 1e-5f);
        size_t base = ((size_t)b * 256 + (t0 + dt)) * 128;
        xn[base + lane]      = f2bf(da * inv * g1[lane] + b1[lane]);
        xn[base + lane + 64] = f2bf(db * inv * g1[lane + 64] + b1[lane + 64]);
    }
}

// ---------------------------------------------------------------------------
// Kernel 2 (MFMA): gx[M,384](bf16) = xn[M,128](bf16) @ Wcat^T + (bih+bhh)
// One block per 128-row m-tile; loops l=0..2 (A staged once, W restaged).
// Gate storage permuted: s = 4*j + gi (j=g&31, gi=g>>5).
// Round-19: epilogue stages the permuted 128x128 tile in w_lds (idle after
// MFMA) then stores coalesced uint4 lines — kills TCC write amplification.
// ---------------------------------------------------------------------------
__global__ __launch_bounds__(256) void k_gemm(const ushort* __restrict__ xn,
                                              const float* __restrict__ Wq,
                                              const float* __restrict__ Wk,
                                              const float* __restrict__ Wv,
                                              const float* __restrict__ bihq, const float* __restrict__ bhhq,
                                              const float* __restrict__ bihk, const float* __restrict__ bhhk,
                                              const float* __restrict__ bihv, const float* __restrict__ bhhv,
                                              ushort* __restrict__ gx) {
    __shared__ ushort a_lds[128 * 136];
    __shared__ ushort w_lds[128 * 136];
    const int tid = threadIdx.x;
    const int m0 = blockIdx.x * 128;

#pragma unroll
    for (int p = 0; p < 8; ++p) {
        int idx = p * 256 + tid;
        int r = idx >> 4, c = idx & 15;
        *(uint4*)&a_lds[r * 136 + c * 8] =
            *(const uint4*)(xn + (size_t)(m0 + r) * 128 + c * 8);
    }

    const int w = tid >> 6, lane = tid & 63;
    const int wr = w >> 1, wc = w & 1;
    const int row16 = lane & 15, koct = lane >> 4;

#pragma unroll 1
    for (int l = 0; l < 3; ++l) {
        const float* W   = (l == 0) ? Wq   : (l == 1) ? Wk   : Wv;
        const float* bih = (l == 0) ? bihq : (l == 1) ? bihk : bihv;
        const float* bhh = (l == 0) ? bhhq : (l == 1) ? bhhk : bhhv;
        __syncthreads();   // previous-l stores (from w_lds) done; safe to restage
#pragma unroll
        for (int p = 0; p < 8; ++p) {
            int idx = p * 256 + tid;
            int r = idx >> 4, c = idx & 15;
            const float* wp = W + (size_t)r * 128 + c * 8;
            float4 wa = *(const float4*)wp;
            float4 wb = *(const float4*)(wp + 4);
            union { ushort u[8]; uint4 v; } pk;
            pk.u[0] = f2bf(wa.x); pk.u[1] = f2bf(wa.y); pk.u[2] = f2bf(wa.z); pk.u[3] = f2bf(wa.w);
            pk.u[4] = f2bf(wb.x); pk.u[5] = f2bf(wb.y); pk.u[6] = f2bf(wb.z); pk.u[7] = f2bf(wb.w);
            *(uint4*)&w_lds[r * 136 + c * 8] = pk.v;
        }
        __syncthreads();

        f32x4 acc[4][4];
#pragma unroll
        for (int mi = 0; mi < 4; ++mi)
#pragma unroll
            for (int ni = 0; ni < 4; ++ni) acc[mi][ni] = (f32x4){0.f, 0.f, 0.f, 0.f};

#pragma unroll
        for (int ki = 0; ki < 4; ++ki) {
            bf16x8 af[4], bfr[4];
#pragma unroll
            for (int mi = 0; mi < 4; ++mi)
                af[mi] = *(const bf16x8*)&a_lds[(wr * 64 + mi * 16 + row16) * 136 + ki * 32 + koct * 8];
#pragma unroll
            for (int ni = 0; ni < 4; ++ni)
                bfr[ni] = *(const bf16x8*)&w_lds[(wc * 64 + ni * 16 + row16) * 136 + ki * 32 + koct * 8];
#pragma unroll
            for (int mi = 0; mi < 4; ++mi)
#pragma unroll
                for (int ni = 0; ni < 4; ++ni)
                    acc[mi][ni] = __builtin_amdgcn_mfma_f32_16x16x32_bf16(af[mi], bfr[ni], acc[mi][ni], 0, 0, 0);
        }
        __syncthreads();   // all w_lds MFMA reads complete (all waves)

        // epilogue: bias + s-permuted write into w_lds (scalar, <=2-way banks)
#pragma unroll
        for (int ni = 0; ni < 4; ++ni) {
            int g = wc * 64 + ni * 16 + row16;         // gate 0..127
            float bsv = bih[g] + bhh[g];
            int j = g & 31, gi = g >> 5;
            int s = j * 4 + gi;
#pragma unroll
            for (int mi = 0; mi < 4; ++mi)
#pragma unroll
                for (int q = 0; q < 4; ++q) {
                    int ml = wr * 64 + mi * 16 + koct * 4 + q;
                    w_lds[ml * 136 + s] = f2bf(acc[mi][ni][q] + bsv);
                }
        }
        __syncthreads();
        // coalesced store: 128 rows x 128 ushorts -> full 64B lines
#pragma unroll
        for (int p = 0; p < 8; ++p) {
            int idx = p * 256 + tid;
            int r = idx >> 4, cchunk = idx & 15;
            *(uint4*)&gx[(size_t)(m0 + r) * 384 + l * 128 + cchunk * 8] =
                *(const uint4*)&w_lds[r * 136 + cchunk * 8];
        }
    }
}

// ---------------------------------------------------------------------------
// Kernel 3 (MFMA LSTM, 2-wave gate-split — exact round-13 version, 147 us):
// block = 128 thr = 2 waves, 16 seqs; plain __syncthreads per step.
// ---------------------------------------------------------------------------
__global__ __launch_bounds__(128, 1) void k_lstm(const ushort* __restrict__ gx,
                                                 const float* __restrict__ Whq,
                                                 const float* __restrict__ Whk,
                                                 const float* __restrict__ Whv,
                                                 ushort* __restrict__ qkv) {
    __shared__ ushort H[2][16][40];   // [parity][b][j], row stride 80B
    const int tid = threadIdx.x;
    const int w = tid >> 6, lane = tid & 63;
    const int r16 = lane & 15, koct = lane >> 4;
    const int l = blockIdx.x >> 6, bgrp = blockIdx.x & 63;
    const int b = bgrp * 16 + r16;
    const float* Wh = (l == 0) ? Whq : (l == 1) ? Whk : Whv;

    bf16x8 wf[4];
#pragma unroll
    for (int gg = 0; gg < 4; ++gg) {
        int g = 4 * w + gg;
        int jA = 8 * (r16 >> 2) + g;
        int giA = r16 & 3;
        const float* wp = Wh + (size_t)(giA * 32 + jA) * 32 + koct * 8;
        float4 wa = *(const float4*)wp;
        float4 wb = *(const float4*)(wp + 4);
        union { ushort u[8]; bf16x8 v; } pk;
        pk.u[0] = f2bf(wa.x); pk.u[1] = f2bf(wa.y); pk.u[2] = f2bf(wa.z); pk.u[3] = f2bf(wa.w);
        pk.u[4] = f2bf(wb.x); pk.u[5] = f2bf(wb.y); pk.u[6] = f2bf(wb.z); pk.u[7] = f2bf(wb.w);
        wf[gg] = pk.v;
    }

    const ushort* gp = gx + (size_t)b * 98304 + l * 128 + koct * 32 + w * 16;
    uint4 pf[4][2];
#pragma unroll
    for (int tt = 0; tt < 4; ++tt) {
        pf[tt][0] = *(const uint4*)(gp + (size_t)tt * 384);
        pf[tt][1] = *(const uint4*)(gp + (size_t)tt * 384 + 8);
    }

    for (int i = tid; i < 320; i += 128) ((uint*)&H[0][0][0])[i] = 0;
    __syncthreads();

    float cst[4] = {0.f, 0.f, 0.f, 0.f};
    ushort* outp = qkv + ((size_t)(l * 1024 + b)) * 8192 + koct * 8 + w * 4;

#pragma unroll 4
    for (int t = 0; t < 256; ++t) {
        const int sl = t & 3;
        const int p = t & 1;
        bf16x8 hf = *(const bf16x8*)&H[p][r16][koct * 8];

        uint u[8];
        u[0] = pf[sl][0].x; u[1] = pf[sl][0].y; u[2] = pf[sl][0].z; u[3] = pf[sl][0].w;
        u[4] = pf[sl][1].x; u[5] = pf[sl][1].y; u[6] = pf[sl][1].z; u[7] = pf[sl][1].w;
        pf[sl][0] = *(const uint4*)(gp + (size_t)(t + 4) * 384);
        pf[sl][1] = *(const uint4*)(gp + (size_t)(t + 4) * 384 + 8);

        f32x4 acc[4];
#pragma unroll
        for (int gg = 0; gg < 4; ++gg)
#pragma unroll
            for (int q = 0; q < 4; ++q) {
                int v = gg * 4 + q;
                uint w32 = u[v >> 1];
                acc[gg][q] = __builtin_bit_cast(float, (v & 1) ? (w32 & 0xffff0000u) : (w32 << 16));
            }
#pragma unroll
        for (int gg = 0; gg < 4; ++gg)
            acc[gg] = __builtin_amdgcn_mfma_f32_16x16x32_bf16(wf[gg], hf, acc[gg], 0, 0, 0);

        float hv[4];
#pragma unroll
        for (int gg = 0; gg < 4; ++gg) {
            float gi = acc[gg][0], gf = acc[gg][1], gg2 = acc[gg][2], go = acc[gg][3];
            float cN = fsig(gf) * cst[gg] + fsig(gi) * ftanh(gg2);
            cst[gg] = cN;
            hv[gg] = fsig(go) * ftanh(cN);
        }
        uint2 hp;
        __asm__ volatile("v_cvt_pk_bf16_f32 %0, %1, %2" : "=v"(hp.x) : "v"(hv[0]), "v"(hv[1]));
        __asm__ volatile("v_cvt_pk_bf16_f32 %0, %1, %2" : "=v"(hp.y) : "v"(hv[2]), "v"(hv[3]));
        *(uint2*)&H[p ^ 1][r16][koct * 8 + w * 4] = hp;
        *(uint2*)(outp + (size_t)t * 32) = hp;
        __syncthreads();
    }
}

// ---------------------------------------------------------------------------
// Kernel 4 (MFMA): attention. 1 block per b, 4 waves x 64 q-rows each.
// ---------------------------------------------------------------------------
__global__ __launch_bounds__(256) void k_attn(const ushort* __restrict__ qkvb,
                                              float* __restrict__ wvout) {
    __shared__ ushort k_sw[256 * 32];      // 16 KiB
    __shared__ ushort vt_sw[32 * 256];     // 16 KiB
    __shared__ ushort p_sw[4][16 * 256];   // 32 KiB (per-wave private)
    const int tid = threadIdx.x, w = tid >> 6, lane = tid & 63;
    const int b = blockIdx.x;
    const ushort* qb = qkvb + (size_t)b * 8192;
    const ushort* kb = qkvb + 8388608 + (size_t)b * 8192;
    const ushort* vb = qkvb + 16777216 + (size_t)b * 8192;
#pragma unroll
    for (int p = 0; p < 4; ++p) {
        int idx = p * 256 + tid;           // 0..1023 chunks of 8 bf16
        int s = idx >> 2, cc = idx & 3;
        uint4 kv = *(const uint4*)(kb + s * 32 + cc * 8);
        int cK = cc ^ ((s >> 1) & 3);
        *(uint4*)&k_sw[s * 32 + cK * 8] = kv;
        uint4 vv = *(const uint4*)(vb + s * 32 + cc * 8);
        union { uint4 v; ushort u[8]; } un; un.v = vv;
#pragma unroll
        for (int e = 0; e < 8; ++e) {
            int row = cc * 8 + e;
            vt_sw[row * 256 + (((s >> 3) ^ (row & 7)) << 3) + (s & 7)] = un.u[e];
        }
    }
    __syncthreads();
    const int r16 = lane & 15, koct = lane >> 4;
    ushort* pw = p_sw[w];
    bf16x8 qf[4];
#pragma unroll
    for (int i = 0; i < 4; ++i) {
        int t = (w * 4 + i) * 16 + r16;
        qf[i] = *(const bf16x8*)(qb + t * 32 + koct * 8);
    }
#pragma unroll 1
    for (int i = 0; i < 4; ++i) {
        const int tb = (w * 4 + i) * 16;
        f32x4 acc[16];
#pragma unroll
        for (int st = 0; st < 16; ++st) acc[st] = (f32x4){0.f, 0.f, 0.f, 0.f};
#pragma unroll
        for (int st = 0; st < 16; ++st) {
            int s = st * 16 + r16;
            int cK = koct ^ ((s >> 1) & 3);
            bf16x8 kf = *(const bf16x8*)&k_sw[s * 32 + cK * 8];
            acc[st] = __builtin_amdgcn_mfma_f32_16x16x32_bf16(qf[i], kf, acc[st], 0, 0, 0);
        }
        float mx[4] = {-1e30f, -1e30f, -1e30f, -1e30f};
#pragma unroll
        for (int st = 0; st < 16; ++st) {
            int s = st * 16 + r16;
#pragma unroll
            for (int q = 0; q < 4; ++q) {
                int t = tb + koct * 4 + q;
                float v = (s <= t) ? acc[st][q] * 0.25f : 0.f;
                acc[st][q] = v;
                mx[q] = fmaxf(mx[q], v);
            }
        }
#pragma unroll
        for (int off = 1; off < 16; off <<= 1)
#pragma unroll
            for (int q = 0; q < 4; ++q) mx[q] = fmaxf(mx[q], __shfl_xor(mx[q], off));
        float sm[4] = {0.f, 0.f, 0.f, 0.f};
#pragma unroll
        for (int st = 0; st < 16; ++st)
#pragma unroll
            for (int q = 0; q < 4; ++q) {
                float p = __expf(acc[st][q] - mx[q]);
                acc[st][q] = p; sm[q] += p;
            }
#pragma unroll
        for (int off = 1; off < 16; off <<= 1)
#pragma unroll
            for (int q = 0; q < 4; ++q) sm[q] += __shfl_xor(sm[q], off);
        float rs[4];
#pragma unroll
        for (int q = 0; q < 4; ++q) rs[q] = __builtin_amdgcn_rcpf(sm[q]);
#pragma unroll
        for (int st = 0; st < 16; ++st) {
            int schunk = st * 2 + (r16 >> 3), sl = r16 & 7;
#pragma unroll
            for (int q = 0; q < 4; ++q) {
                int tl = koct * 4 + q;
                pw[tl * 256 + ((schunk ^ (tl & 7)) << 3) + sl] = f2bf(acc[st][q] * rs[q]);
            }
        }
        __asm__ volatile("s_waitcnt lgkmcnt(0)" ::: "memory");
        f32x4 oa[2];
        oa[0] = (f32x4){0.f, 0.f, 0.f, 0.f};
        oa[1] = (f32x4){0.f, 0.f, 0.f, 0.f};
#pragma unroll
        for (int ks = 0; ks < 8; ++ks) {
            int kc = ks * 4 + koct;
            bf16x8 pa = *(const bf16x8*)&pw[r16 * 256 + ((kc ^ (r16 & 7)) << 3)];
#pragma unroll
            for (int n = 0; n < 2; ++n) {
                int row = n * 16 + r16;
                bf16x8 vf = *(const bf16x8*)&vt_sw[row * 256 + ((kc ^ (row & 7)) << 3)];
                oa[n] = __builtin_amdgcn_mfma_f32_16x16x32_bf16(pa, vf, oa[n], 0, 0, 0);
            }
        }
#pragma unroll
        for (int n = 0; n < 2; ++n)
#pragma unroll
            for (int q = 0; q < 4; ++q)
                wvout[((size_t)b * 256 + tb + koct * 4 + q) * 32 + n * 16 + r16] = oa[n][q];
    }
}

// ---------------------------------------------------------------------------
// Kernel 5 (round-13): LN2 + complex linear via MFMA (K=32) + one-pass LN3
// + PReLU + residual.
// ---------------------------------------------------------------------------
__global__ __launch_bounds__(256) void k_post(const float* __restrict__ wv,
                                              const float* __restrict__ in,
                                              const float* __restrict__ g2,
                                              const float* __restrict__ b2,
                                              const float* __restrict__ Wr,
                                              const float* __restrict__ br,
                                              const float* __restrict__ Wi,
                                              const float* __restrict__ bi,
                                              const float* __restrict__ g3,
                                              const float* __restrict__ b3,
                                              const float* __restrict__ pa,
                                              float* __restrict__ outp) {
    __shared__ float xv[32][36];          // 144B row stride
    __shared__ float out_s[64][65];
    const int tid = threadIdx.x;
    const int n = blockIdx.z, f = blockIdx.y, t0 = blockIdx.x * 32;
    const int b = n * 256 + f;
    const int lane = tid & 63, w = tid >> 6;
    const int r16 = lane & 15, koct = lane >> 4;
    const int tt = w & 1, ri = w >> 1;

    for (int idx = tid; idx < 1024; idx += 256) {
        int dt = idx >> 5, j = idx & 31;
        xv[dt][j] = wv[((size_t)b * 256 + t0 + dt) * 32 + j];
    }

    bf16x8 bfr[4];
    float bias_v[4], g3v[4], b3v[4];
    const int kofs = (koct < 2) ? koct * 8 : (koct - 2) * 8;
#pragma unroll
    for (int ct = 0; ct < 4; ++ct) {
        int c = ct * 16 + r16;
        const float* srcW = (ri == 0) ? ((koct < 2) ? Wr : Wi)
                                      : ((koct < 2) ? Wi : Wr);
        float sgn = (ri == 0 && koct >= 2) ? -1.f : 1.f;
        float4 wa = *(const float4*)(srcW + c * 16 + kofs);
        float4 wb = *(const float4*)(srcW + c * 16 + kofs + 4);
        union { ushort u[8]; bf16x8 v; } pk;
        pk.u[0] = f2bf(sgn * wa.x); pk.u[1] = f2bf(sgn * wa.y);
        pk.u[2] = f2bf(sgn * wa.z); pk.u[3] = f2bf(sgn * wa.w);
        pk.u[4] = f2bf(sgn * wb.x); pk.u[5] = f2bf(sgn * wb.y);
        pk.u[6] = f2bf(sgn * wb.z); pk.u[7] = f2bf(sgn * wb.w);
        bfr[ct] = pk.v;
        bias_v[ct] = (ri == 0) ? (br[c] - bi[c]) : (br[c] + bi[c]);
        g3v[ct] = g3[c];
        b3v[ct] = b3[c];
    }
    const float alpha = pa[0];
    __syncthreads();

#pragma unroll 1
    for (int r = 0; r < 4; ++r) {
        int dt = w * 8 + r * 2 + (lane >> 5);
        int j = lane & 31;
        float v = xv[dt][j];
        float mean = hredsum(v) * 0.03125f;
        float d = v - mean;
        float var = hredsum(d * d) * 0.03125f;
        float inv = __builtin_amdgcn_rsqf(var + 1e-5f);
        xv[dt][j] = d * inv * g2[j] + b2[j];
    }
    __syncthreads();

    const float* xrow = &xv[tt * 16 + r16][koct * 8];
    float4 a0 = *(const float4*)xrow;
    float4 a1 = *(const float4*)(xrow + 4);
    uint4 ap;
    __asm__ volatile("v_cvt_pk_bf16_f32 %0, %1, %2" : "=v"(ap.x) : "v"(a0.x), "v"(a0.y));
    __asm__ volatile("v_cvt_pk_bf16_f32 %0, %1, %2" : "=v"(ap.y) : "v"(a0.z), "v"(a0.w));
    __asm__ volatile("v_cvt_pk_bf16_f32 %0, %1, %2" : "=v"(ap.z) : "v"(a1.x), "v"(a1.y));
    __asm__ volatile("v_cvt_pk_bf16_f32 %0, %1, %2" : "=v"(ap.w) : "v"(a1.z), "v"(a1.w));
    bf16x8 af = __builtin_bit_cast(bf16x8, ap);

    f32x4 acc[4];
#pragma unroll
    for (int ct = 0; ct < 4; ++ct) {
        acc[ct] = (f32x4){0.f, 0.f, 0.f, 0.f};
        acc[ct] = __builtin_amdgcn_mfma_f32_16x16x32_bf16(af, bfr[ct], acc[ct], 0, 0, 0);
    }

    float val[4][4];
    float s[4] = {0.f, 0.f, 0.f, 0.f}, sq[4] = {0.f, 0.f, 0.f, 0.f};
#pragma unroll
    for (int ct = 0; ct < 4; ++ct)
#pragma unroll
        for (int q = 0; q < 4; ++q) {
            float v = acc[ct][q] + bias_v[ct];
            val[ct][q] = v;
            s[q] += v;
            sq[q] += v * v;
        }
#pragma unroll
    for (int off = 1; off < 16; off <<= 1)
#pragma unroll
        for (int q = 0; q < 4; ++q) {
            s[q]  += __shfl_xor(s[q], off);
            sq[q] += __shfl_xor(sq[q], off);
        }
#pragma unroll
    for (int q = 0; q < 4; ++q) {
        float m = s[q] * 0.015625f;
        float var = fmaxf(sq[q] * 0.015625f - m * m, 0.f);
        float inv = __builtin_amdgcn_rsqf(var + 1e-5f);
        int t2 = (tt * 16 + koct * 4 + q) * 2 + ri;
#pragma unroll
        for (int ct = 0; ct < 4; ++ct) {
            float nv = (val[ct][q] - m) * inv * g3v[ct] + b3v[ct];
            nv = (nv >= 0.f) ? nv : alpha * nv;
            out_s[ct * 16 + r16][t2] = nv;
        }
    }
    __syncthreads();

    const int cc = tid >> 2, q = tid & 3;
    size_t base = ((size_t)(n * 64 + cc) * 256 + f) * 512 + t0 * 2 + q * 16;
#pragma unroll
    for (int e = 0; e < 4; ++e) {
        float4 iv = *(const float4*)(in + base + e * 4);
        int k0 = q * 16 + e * 4;
        float4 ov;
        ov.x = out_s[cc][k0]     + iv.x;
        ov.y = out_s[cc][k0 + 1] + iv.y;
        ov.z = out_s[cc][k0 + 2] + iv.z;
        ov.w = out_s[cc][k0 + 3] + iv.w;
        *(float4*)(outp + base + e * 4) = ov;
    }
}

// ---------------------------------------------------------------------------
extern "C" void kernel_launch(void* const* d_in, const int* in_sizes, int n_in,
                              void* d_out, int out_size, void* d_ws, size_t ws_size,
                              hipStream_t stream) {
    const float* in   = (const float*)d_in[0];
    const float* g1   = (const float*)d_in[1];
    const float* b1   = (const float*)d_in[2];
    const float* Wq   = (const float*)d_in[3];
    const float* Whq  = (const float*)d_in[4];
    const float* bihq = (const float*)d_in[5];
    const float* bhhq = (const float*)d_in[6];
    const float* Wk   = (const float*)d_in[7];
    const float* Whk  = (const float*)d_in[8];
    const float* bihk = (const float*)d_in[9];
    const float* bhhk = (const float*)d_in[10];
    const float* Wv   = (const float*)d_in[11];
    const float* Whv  = (const float*)d_in[12];
    const float* bihv = (const float*)d_in[13];
    const float* bhhv = (const float*)d_in[14];
    const float* g2   = (const float*)d_in[15];
    const float* b2   = (const float*)d_in[16];
    const float* Wr   = (const float*)d_in[17];
    const float* br   = (const float*)d_in[18];
    const float* Wi   = (const float*)d_in[19];
    const float* bi   = (const float*)d_in[20];
    const float* g3   = (const float*)d_in[21];
    const float* b3   = (const float*)d_in[22];
    const float* pa   = (const float*)d_in[23];
    float* outp = (float*)d_out;

    // workspace layout (bytes):
    // [0, 201326592)            gx  bf16  262144*384*2
    // [201326592, 268435456)    xn  bf16  262144*128*2
    // [268435456, 318767104)    qkv bf16  3*262144*32*2
    // [318767104, 352321536)    wv  fp32  262144*32*4
    ushort* gxb  = (ushort*)d_ws;
    ushort* xnb  = (ushort*)((char*)d_ws + 201326592);
    ushort* qkvb = (ushort*)((char*)d_ws + 268435456);
    float*  wvb  = (float*)((char*)d_ws + 318767104);

    k_prep<<<dim3(8, 256, 4), dim3(256), 0, stream>>>(in, g1, b1, xnb);
    k_gemm<<<dim3(2048), dim3(256), 0, stream>>>(xnb, Wq, Wk, Wv,
                                                 bihq, bhhq, bihk, bhhk, bihv, bhhv, gxb);
    k_lstm<<<dim3(192), dim3(128), 0, stream>>>(gxb, Whq, Whk, Whv, qkvb);
    k_attn<<<dim3(1024), dim3(256), 0, stream>>>(qkvb, wvb);
    k_post<<<dim3(8, 256, 4), dim3(256), 0, stream>>>(wvb, in, g2, b2,
                                                      Wr, br, Wi, bi, g3, b3, pa, outp);
}